// Round 2
// baseline (283.637 us; speedup 1.0000x reference)
//
#include <hip/hip_runtime.h>
#include <hip/hip_bf16.h>
#include <cstdint>
#include <cstddef>

// Problem constants
#define B_  2
#define T_  2048
#define C_  1024
#define H_  16
#define D_  64
#define NEG_INF_ -1e9f

typedef short bf16x8 __attribute__((ext_vector_type(8)));
typedef float f32x4  __attribute__((ext_vector_type(4)));

__device__ __forceinline__ short f2bf(float f) {
  union { float f; unsigned u; } x; x.f = f;
  unsigned r = (x.u + 0x7fffu + ((x.u >> 16) & 1u)) >> 16;  // RNE
  return (short)r;
}

__device__ __forceinline__ void gload16(const void* g, void* l) {
  // async global->LDS, 16B per lane; LDS dest = wave-uniform base + lane*16
  __builtin_amdgcn_global_load_lds(
      (const __attribute__((address_space(1))) unsigned int*)g,
      (__attribute__((address_space(3))) unsigned int*)l, 16, 0, 0);
}

// ---------------- fp32 -> bf16 convert (vectorized) ----------------
__global__ __launch_bounds__(256) void cvt_bf16(const float* __restrict__ in,
                                                short* __restrict__ out, int n4) {
  int i = blockIdx.x * 256 + threadIdx.x;
  if (i < n4) {
    float4 v = ((const float4*)in)[i];
    short4 o;
    o.x = f2bf(v.x); o.y = f2bf(v.y); o.z = f2bf(v.z); o.w = f2bf(v.w);
    ((short4*)out)[i] = o;
  }
}

// ---------------- transpose + convert: in[R][C] fp32 -> out[C][R] bf16 ------
__global__ __launch_bounds__(256) void transpose_cvt(const float* __restrict__ in,
                                                     short* __restrict__ out,
                                                     int R, int C) {
  __shared__ float tile[32][33];
  int gx = blockIdx.x * 32, gy = blockIdx.y * 32;
  int tx = threadIdx.x, ty = threadIdx.y;  // (32,8)
#pragma unroll
  for (int i = 0; i < 4; ++i)
    tile[ty + i * 8][tx] = in[(size_t)(gy + ty + i * 8) * C + gx + tx];
  __syncthreads();
#pragma unroll
  for (int i = 0; i < 4; ++i)
    out[(size_t)(gx + ty + i * 8) * R + gy + tx] = f2bf(tile[tx][ty + i * 8]);
}

// ---------------- T5 bias table: bias[h][dist], dist in [0,2048) -----------
__global__ __launch_bounds__(256) void bias_table(const float* __restrict__ rel_table,
                                                  float* __restrict__ btab) {
  int idx = blockIdx.x * 256 + threadIdx.x;  // 16*2048
  if (idx >= H_ * T_) return;
  int dist = idx & (T_ - 1);
  int h = idx >> 11;
  int bucket;
  if (dist < 16) {
    bucket = dist;
  } else {
    float rp = (float)dist;
    int large = 16 + (int)(logf(rp * (1.0f / 16.0f)) * (1.0f / logf(128.0f)) * 16.0f);
    bucket = large < 31 ? large : 31;
  }
  btab[idx] = rel_table[bucket * H_ + h];
}

// ---------------- bf16 GEMM: C[M,N] = A[M,K] * Bt[N,K]^T -------------------
// 128x128 tile, BK=64, 4 waves, 16x16x32 MFMA, global_load_lds(16),
// XOR-swizzled LDS (rows are 128B -> swizzle byte ^= (row&7)<<4).
// MODE 0: scatter epilogue -> q(bf16,*0.125)/k(bf16)/vT(bf16 transposed)
// MODE 1: fp32 out
template <int MODE>
__global__ __launch_bounds__(256) void gemm_bt128(
    const short* __restrict__ A, const short* __restrict__ Bt,
    int M, int N, int K,
    short* __restrict__ q_out, short* __restrict__ k_out,
    short* __restrict__ vT_out, float* __restrict__ f_out) {
  __shared__ alignas(16) short As[128 * 64];
  __shared__ alignas(16) short Bs[128 * 64];
  const int tid = threadIdx.x;
  const int w = tid >> 6, lane = tid & 63;
  const int g = lane >> 4, l16 = lane & 15;
  const int wr = w >> 1, wc = w & 1;
  const int m0 = blockIdx.y * 128, n0 = blockIdx.x * 128;

  const char* Ag = (const char*)(A + (size_t)m0 * K);
  const char* Bg = (const char*)(Bt + (size_t)n0 * K);
  char* AsB = (char*)As;
  char* BsB = (char*)Bs;

  // staging: 1024 16B-chunks per tile, 4 per thread; pre-swizzle source chunk
  int goff[4];
#pragma unroll
  for (int i = 0; i < 4; ++i) {
    int o = i * 256 + tid;
    int row = o >> 3, ch = o & 7;
    goff[i] = row * (K * 2) + ((ch ^ (row & 7)) << 4);
  }

  f32x4 acc[4][4] = {};

  const int nkt = K >> 6;
  for (int kt = 0; kt < nkt; ++kt) {
    __syncthreads();
    const int kbyte = kt << 7;
#pragma unroll
    for (int i = 0; i < 4; ++i)
      gload16(Ag + goff[i] + kbyte, AsB + i * 4096 + w * 1024);
#pragma unroll
    for (int i = 0; i < 4; ++i)
      gload16(Bg + goff[i] + kbyte, BsB + i * 4096 + w * 1024);
    __syncthreads();
#pragma unroll
    for (int kk = 0; kk < 2; ++kk) {
      bf16x8 af[4], bff[4];
#pragma unroll
      for (int m = 0; m < 4; ++m) {
        int r = wr * 64 + m * 16 + l16;
        int off = (r * 128 + kk * 64 + g * 16) ^ ((r & 7) << 4);
        af[m] = *(const bf16x8*)(AsB + off);
      }
#pragma unroll
      for (int n = 0; n < 4; ++n) {
        int c = wc * 64 + n * 16 + l16;
        int off = (c * 128 + kk * 64 + g * 16) ^ ((c & 7) << 4);
        bff[n] = *(const bf16x8*)(BsB + off);
      }
#pragma unroll
      for (int m = 0; m < 4; ++m)
#pragma unroll
        for (int n = 0; n < 4; ++n)
          acc[m][n] = __builtin_amdgcn_mfma_f32_16x16x32_bf16(af[m], bff[n], acc[m][n], 0, 0, 0);
    }
  }

  // epilogue: C/D layout col=lane&15, row=(lane>>4)*4+r
#pragma unroll
  for (int m = 0; m < 4; ++m) {
#pragma unroll
    for (int n = 0; n < 4; ++n) {
      const int colg = n0 + wc * 64 + n * 16 + l16;
#pragma unroll
      for (int r = 0; r < 4; ++r) {
        const int rowg = m0 + wr * 64 + m * 16 + g * 4 + r;
        float v = acc[m][n][r];
        if (MODE == 1) {
          f_out[(size_t)rowg * N + colg] = v;
        } else {
          int part = colg >> 10;
          int within = colg & 1023;
          int h = within >> 6, dd = within & 63;
          int b = rowg >> 11, t = rowg & (T_ - 1);
          size_t bh = (size_t)(b * H_ + h);
          if (part == 0)
            q_out[(bh * T_ + t) * D_ + dd] = f2bf(v * 0.125f);  // fold 1/sqrt(d)
          else if (part == 1)
            k_out[(bh * T_ + t) * D_ + dd] = f2bf(v);
          else
            vT_out[(bh * D_ + dd) * T_ + t] = f2bf(v);  // V transposed
        }
      }
    }
  }
}

// ---------------- flash attention with T5 bias, causal ---------------------
// 4 waves/block; wave w owns 16 q-rows; Q-tile 64, KV-tile 64.
// q pre-scaled by 0.125. K staged [kv][64d], V staged transposed [d][64kv],
// both XOR-swizzled. P round-trips through wave-private LDS.
__global__ __launch_bounds__(256) void attn64(
    const short* __restrict__ qb, const short* __restrict__ kb,
    const short* __restrict__ vTb, const float* __restrict__ bias_tab,
    short* __restrict__ yb) {
  __shared__ alignas(16) short Ks[64 * 64];
  __shared__ alignas(16) short Vs[64 * 64];
  __shared__ alignas(16) short Ps[4][16 * 64];
  const int tid = threadIdx.x;
  const int w = tid >> 6, lane = tid & 63;
  const int g = lane >> 4, l16 = lane & 15;
  const int bh = blockIdx.y;          // b*16 + h
  const int h = bh & (H_ - 1);
  const int b = bh >> 4;
  const int qt = blockIdx.x;
  const int q0 = qt * 64;

  const char* kbase = (const char*)(kb + (size_t)bh * T_ * D_);
  const char* vbase = (const char*)(vTb + (size_t)bh * D_ * T_);
  const float* btab = bias_tab + h * T_;

  // Q fragments (A-operand): lane holds row l16, d = c*32 + g*8 + j
  bf16x8 qf[2];
  {
    const short* qrow = qb + ((size_t)bh * T_ + q0 + w * 16 + l16) * D_;
    qf[0] = *(const bf16x8*)(qrow + g * 8);
    qf[1] = *(const bf16x8*)(qrow + 32 + g * 8);
  }

  f32x4 acc[4] = {};
  float mrun[4], lrun[4];
#pragma unroll
  for (int r = 0; r < 4; ++r) { mrun[r] = -1e30f; lrun[r] = 0.f; }

  char* KsB = (char*)Ks;
  char* VsB = (char*)Vs;
  char* PsB = (char*)&Ps[w][0];

  int krow[2], kch[2];
#pragma unroll
  for (int i = 0; i < 2; ++i) {
    int o = i * 256 + tid;
    krow[i] = o >> 3;
    kch[i] = (o & 7) ^ (krow[i] & 7);
  }

  const int ntiles = qt + 1;
  for (int t = 0; t < ntiles; ++t) {
    const int kv0 = t * 64;
    __syncthreads();
#pragma unroll
    for (int i = 0; i < 2; ++i)
      gload16(kbase + (size_t)(kv0 + krow[i]) * 128 + kch[i] * 16,
              KsB + i * 4096 + w * 1024);
#pragma unroll
    for (int i = 0; i < 2; ++i)
      gload16(vbase + (size_t)krow[i] * (T_ * 2) + kv0 * 2 + kch[i] * 16,
              VsB + i * 4096 + w * 1024);
    __syncthreads();

    // S = Q*K^T  (4 kv-groups of 16)
    f32x4 s[4];
#pragma unroll
    for (int n = 0; n < 4; ++n) {
      int kvrow = n * 16 + l16;
      int off0 = (kvrow * 128 + g * 16) ^ ((kvrow & 7) << 4);
      int off1 = (kvrow * 128 + 64 + g * 16) ^ ((kvrow & 7) << 4);
      bf16x8 k0 = *(const bf16x8*)(KsB + off0);
      bf16x8 k1 = *(const bf16x8*)(KsB + off1);
      f32x4 z = {};
      z = __builtin_amdgcn_mfma_f32_16x16x32_bf16(qf[0], k0, z, 0, 0, 0);
      z = __builtin_amdgcn_mfma_f32_16x16x32_bf16(qf[1], k1, z, 0, 0, 0);
      s[n] = z;
    }

    // bias + causal mask; per-row tile max
    float sv[4][4];
    float tmax[4] = {-1e30f, -1e30f, -1e30f, -1e30f};
#pragma unroll
    for (int n = 0; n < 4; ++n) {
      int kvg = kv0 + n * 16 + l16;
#pragma unroll
      for (int r = 0; r < 4; ++r) {
        int qg = q0 + w * 16 + g * 4 + r;
        int dist = qg - kvg;
        float val = s[n][r] + (dist >= 0 ? btab[dist] : NEG_INF_);
        sv[n][r] = val;
        tmax[r] = fmaxf(tmax[r], val);
      }
    }
#pragma unroll
    for (int r = 0; r < 4; ++r) {
      float v = tmax[r];
      v = fmaxf(v, __shfl_xor(v, 1));
      v = fmaxf(v, __shfl_xor(v, 2));
      v = fmaxf(v, __shfl_xor(v, 4));
      v = fmaxf(v, __shfl_xor(v, 8));
      tmax[r] = v;
    }

    // online softmax update + write P to wave-private LDS (swizzled)
    float lt[4];
#pragma unroll
    for (int r = 0; r < 4; ++r) {
      float mnew = fmaxf(mrun[r], tmax[r]);
      float scale = __expf(mrun[r] - mnew);
      mrun[r] = mnew;
      lrun[r] *= scale;
#pragma unroll
      for (int dn = 0; dn < 4; ++dn) acc[dn][r] *= scale;
      float su = 0.f;
#pragma unroll
      for (int n = 0; n < 4; ++n) {
        float p = __expf(sv[n][r] - mnew);
        su += p;
        int row = g * 4 + r, col = n * 16 + l16;
        int off = (row * 128 + col * 2) ^ ((row & 7) << 4);
        *(short*)(PsB + off) = f2bf(p);
      }
      lt[r] = su;
    }
#pragma unroll
    for (int r = 0; r < 4; ++r) {
      float v = lt[r];
      v += __shfl_xor(v, 1);
      v += __shfl_xor(v, 2);
      v += __shfl_xor(v, 4);
      v += __shfl_xor(v, 8);
      lrun[r] += v;
    }

    // O += P*V   (P from LDS as A-frag; V^T rows as B-frag)
    bf16x8 pf[2];
    {
      int prow = l16;
      int o0 = (prow * 128 + g * 16) ^ ((prow & 7) << 4);
      int o1 = (prow * 128 + 64 + g * 16) ^ ((prow & 7) << 4);
      pf[0] = *(const bf16x8*)(PsB + o0);
      pf[1] = *(const bf16x8*)(PsB + o1);
    }
#pragma unroll
    for (int dn = 0; dn < 4; ++dn) {
      int drow = dn * 16 + l16;
      int o0 = (drow * 128 + g * 16) ^ ((drow & 7) << 4);
      int o1 = (drow * 128 + 64 + g * 16) ^ ((drow & 7) << 4);
      bf16x8 v0 = *(const bf16x8*)(VsB + o0);
      bf16x8 v1 = *(const bf16x8*)(VsB + o1);
      acc[dn] = __builtin_amdgcn_mfma_f32_16x16x32_bf16(pf[0], v0, acc[dn], 0, 0, 0);
      acc[dn] = __builtin_amdgcn_mfma_f32_16x16x32_bf16(pf[1], v1, acc[dn], 0, 0, 0);
    }
  }

  // epilogue: y[b][t][h*64+d] bf16
#pragma unroll
  for (int r = 0; r < 4; ++r) {
    int qg = q0 + w * 16 + g * 4 + r;
    float inv = 1.0f / lrun[r];
    size_t ybase = ((size_t)b * T_ + qg) * C_ + h * D_;
#pragma unroll
    for (int dn = 0; dn < 4; ++dn)
      yb[ybase + dn * 16 + l16] = f2bf(acc[dn][r] * inv);
  }
}

// ---------------------------------------------------------------------------
extern "C" void kernel_launch(void* const* d_in, const int* in_sizes, int n_in,
                              void* d_out, int out_size, void* d_ws, size_t ws_size,
                              hipStream_t stream) {
  const float* x = (const float*)d_in[0];         // [2,2048,1024]
  const float* w_qkv = (const float*)d_in[1];     // [1024,3072]
  const float* w_proj = (const float*)d_in[2];    // [1024,1024]
  const float* rel_table = (const float*)d_in[3]; // [32,16]
  float* out = (float*)d_out;                     // [2,2048,1024]

  const size_t MB = 1024 * 1024;
  char* ws = (char*)d_ws;
  short* xb     = (short*)(ws);             // 8 MB  [4096,1024] bf16
  short* wqkvT  = (short*)(ws + 8 * MB);    // 6 MB  [3072,1024] bf16
  short* wprojT = (short*)(ws + 14 * MB);   // 2 MB  [1024,1024] bf16
  short* qb     = (short*)(ws + 16 * MB);   // 8 MB  [B,H,T,64] bf16 (pre-scaled)
  short* kbuf   = (short*)(ws + 24 * MB);   // 8 MB  [B,H,T,64] bf16
  short* vT     = (short*)(ws + 32 * MB);   // 8 MB  [B,H,64,T] bf16
  short* yb     = (short*)(ws + 40 * MB);   // 8 MB  [4096,1024] bf16
  float* btab   = (float*)(ws + 48 * MB);   // 128 KB [16,2048] fp32

  // 1. conversions
  cvt_bf16<<<4096, 256, 0, stream>>>(x, xb, (B_ * T_ * C_) / 4);
  dim3 tb(32, 8);
  transpose_cvt<<<dim3(96, 32), tb, 0, stream>>>(w_qkv, wqkvT, 1024, 3072);
  transpose_cvt<<<dim3(32, 32), tb, 0, stream>>>(w_proj, wprojT, 1024, 1024);
  bias_table<<<128, 256, 0, stream>>>(rel_table, btab);

  // 2. qkv = x @ w_qkv  (scatter to q/k/vT)
  gemm_bt128<0><<<dim3(24, 32), 256, 0, stream>>>(xb, wqkvT, 4096, 3072, 1024,
                                                  qb, kbuf, vT, nullptr);
  // 3. attention
  attn64<<<dim3(32, 32), 256, 0, stream>>>(qb, kbuf, vT, btab, yb);

  // 4. out = y @ w_proj
  gemm_bt128<1><<<dim3(8, 32), 256, 0, stream>>>(yb, wprojT, 4096, 1024, 1024,
                                                 nullptr, nullptr, nullptr, out);
}

// Round 3
// 276.707 us; speedup vs baseline: 1.0250x; 1.0250x over previous
//
#include <hip/hip_runtime.h>
#include <hip/hip_bf16.h>
#include <cstdint>
#include <cstddef>

// Problem constants
#define B_  2
#define T_  2048
#define C_  1024
#define H_  16
#define D_  64
#define NEG_INF_ -1e9f

typedef short bf16x8 __attribute__((ext_vector_type(8)));
typedef float f32x4  __attribute__((ext_vector_type(4)));

__device__ __forceinline__ short f2bf(float f) {
  union { float f; unsigned u; } x; x.f = f;
  unsigned r = (x.u + 0x7fffu + ((x.u >> 16) & 1u)) >> 16;  // RNE
  return (short)r;
}

__device__ __forceinline__ void gload16(const void* g, void* l) {
  // async global->LDS, 16B per lane; LDS dest = wave-uniform base + lane*16
  __builtin_amdgcn_global_load_lds(
      (const __attribute__((address_space(1))) unsigned int*)g,
      (__attribute__((address_space(3))) unsigned int*)l, 16, 0, 0);
}

// ---------------- fp32 -> bf16 convert (vectorized) ----------------
__global__ __launch_bounds__(256) void cvt_bf16(const float* __restrict__ in,
                                                short* __restrict__ out, int n4) {
  int i = blockIdx.x * 256 + threadIdx.x;
  if (i < n4) {
    float4 v = ((const float4*)in)[i];
    short4 o;
    o.x = f2bf(v.x); o.y = f2bf(v.y); o.z = f2bf(v.z); o.w = f2bf(v.w);
    ((short4*)out)[i] = o;
  }
}

// ---------------- transpose + convert: in[R][C] fp32 -> out[C][R] bf16 ------
__global__ __launch_bounds__(256) void transpose_cvt(const float* __restrict__ in,
                                                     short* __restrict__ out,
                                                     int R, int C) {
  __shared__ float tile[32][33];
  int gx = blockIdx.x * 32, gy = blockIdx.y * 32;
  int tx = threadIdx.x, ty = threadIdx.y;  // (32,8)
#pragma unroll
  for (int i = 0; i < 4; ++i)
    tile[ty + i * 8][tx] = in[(size_t)(gy + ty + i * 8) * C + gx + tx];
  __syncthreads();
#pragma unroll
  for (int i = 0; i < 4; ++i)
    out[(size_t)(gx + ty + i * 8) * R + gy + tx] = f2bf(tile[tx][ty + i * 8]);
}

// ---------------- T5 bias table: bias[h][dist], dist in [0,2048) -----------
__global__ __launch_bounds__(256) void bias_table(const float* __restrict__ rel_table,
                                                  float* __restrict__ btab) {
  int idx = blockIdx.x * 256 + threadIdx.x;  // 16*2048
  if (idx >= H_ * T_) return;
  int dist = idx & (T_ - 1);
  int h = idx >> 11;
  int bucket;
  if (dist < 16) {
    bucket = dist;
  } else {
    float rp = (float)dist;
    int large = 16 + (int)(logf(rp * (1.0f / 16.0f)) * (1.0f / logf(128.0f)) * 16.0f);
    bucket = large < 31 ? large : 31;
  }
  btab[idx] = rel_table[bucket * H_ + h];
}

// ---------------- bf16 GEMM: C[M,N] = A[M,K] * Bt[N,K]^T -------------------
// 128x128 tile, BK=64, 4 waves, 16x16x32 MFMA, global_load_lds(16),
// XOR-swizzled LDS (rows are 128B -> swizzle byte ^= (row&7)<<4).
// MODE 0: scatter epilogue -> q(bf16,*0.125)/k(bf16)/vT(bf16 transposed)
// MODE 1: fp32 out
template <int MODE>
__global__ __launch_bounds__(256) void gemm_bt128(
    const short* __restrict__ A, const short* __restrict__ Bt,
    int M, int N, int K,
    short* __restrict__ q_out, short* __restrict__ k_out,
    short* __restrict__ vT_out, float* __restrict__ f_out) {
  __shared__ alignas(16) short As[128 * 64];
  __shared__ alignas(16) short Bs[128 * 64];
  const int tid = threadIdx.x;
  const int w = tid >> 6, lane = tid & 63;
  const int g = lane >> 4, l16 = lane & 15;
  const int wr = w >> 1, wc = w & 1;
  const int m0 = blockIdx.y * 128, n0 = blockIdx.x * 128;

  const char* Ag = (const char*)(A + (size_t)m0 * K);
  const char* Bg = (const char*)(Bt + (size_t)n0 * K);
  char* AsB = (char*)As;
  char* BsB = (char*)Bs;

  // staging: 1024 16B-chunks per tile, 4 per thread; pre-swizzle source chunk
  int goff[4];
#pragma unroll
  for (int i = 0; i < 4; ++i) {
    int o = i * 256 + tid;
    int row = o >> 3, ch = o & 7;
    goff[i] = row * (K * 2) + ((ch ^ (row & 7)) << 4);
  }

  f32x4 acc[4][4] = {};

  const int nkt = K >> 6;
  for (int kt = 0; kt < nkt; ++kt) {
    __syncthreads();
    const int kbyte = kt << 7;
#pragma unroll
    for (int i = 0; i < 4; ++i)
      gload16(Ag + goff[i] + kbyte, AsB + i * 4096 + w * 1024);
#pragma unroll
    for (int i = 0; i < 4; ++i)
      gload16(Bg + goff[i] + kbyte, BsB + i * 4096 + w * 1024);
    __syncthreads();
#pragma unroll
    for (int kk = 0; kk < 2; ++kk) {
      bf16x8 af[4], bff[4];
#pragma unroll
      for (int m = 0; m < 4; ++m) {
        int r = wr * 64 + m * 16 + l16;
        int off = (r * 128 + kk * 64 + g * 16) ^ ((r & 7) << 4);
        af[m] = *(const bf16x8*)(AsB + off);
      }
#pragma unroll
      for (int n = 0; n < 4; ++n) {
        int c = wc * 64 + n * 16 + l16;
        int off = (c * 128 + kk * 64 + g * 16) ^ ((c & 7) << 4);
        bff[n] = *(const bf16x8*)(BsB + off);
      }
#pragma unroll
      for (int m = 0; m < 4; ++m)
#pragma unroll
        for (int n = 0; n < 4; ++n)
          acc[m][n] = __builtin_amdgcn_mfma_f32_16x16x32_bf16(af[m], bff[n], acc[m][n], 0, 0, 0);
    }
  }

  // epilogue: C/D layout col=lane&15, row=(lane>>4)*4+r
#pragma unroll
  for (int m = 0; m < 4; ++m) {
#pragma unroll
    for (int n = 0; n < 4; ++n) {
      const int colg = n0 + wc * 64 + n * 16 + l16;
#pragma unroll
      for (int r = 0; r < 4; ++r) {
        const int rowg = m0 + wr * 64 + m * 16 + g * 4 + r;
        float v = acc[m][n][r];
        if (MODE == 1) {
          f_out[(size_t)rowg * N + colg] = v;
        } else {
          int part = colg >> 10;
          int within = colg & 1023;
          int h = within >> 6, dd = within & 63;
          int b = rowg >> 11, t = rowg & (T_ - 1);
          size_t bh = (size_t)(b * H_ + h);
          if (part == 0)
            q_out[(bh * T_ + t) * D_ + dd] = f2bf(v * 0.125f);  // fold 1/sqrt(d)
          else if (part == 1)
            k_out[(bh * T_ + t) * D_ + dd] = f2bf(v);
          else
            vT_out[(bh * D_ + dd) * T_ + t] = f2bf(v);  // V transposed
        }
      }
    }
  }
}

// ---------------- flash attention with T5 bias, causal ---------------------
// 4 waves/block; wave w owns 16 q-rows; Q-tile 64, KV-tile 64.
// 2-phase double-buffered K/V staging (issue next-tile gload_lds BEFORE
// computing current tile; __syncthreads' implicit vmcnt(0) drain lands after
// compute has hidden the latency). Bias comes from a per-tile 127-entry LDS
// window (NEG_INF pre-folded for masked dist<0) instead of per-element VMEM.
__global__ __launch_bounds__(256) void attn64(
    const short* __restrict__ qb, const short* __restrict__ kb,
    const short* __restrict__ vTb, const float* __restrict__ bias_tab,
    short* __restrict__ yb) {
  __shared__ alignas(16) short Ks[2][64 * 64];
  __shared__ alignas(16) short Vs[2][64 * 64];
  __shared__ alignas(16) short Ps[4][16 * 64];
  __shared__ float biasw[2][128];
  const int tid = threadIdx.x;
  const int w = tid >> 6, lane = tid & 63;
  const int g = lane >> 4, l16 = lane & 15;
  const int bh = blockIdx.y;          // b*16 + h
  const int h = bh & (H_ - 1);
  const int b = bh >> 4;
  const int qt = blockIdx.x;
  const int q0 = qt * 64;

  const char* kbase = (const char*)(kb + (size_t)bh * T_ * D_);
  const char* vbase = (const char*)(vTb + (size_t)bh * D_ * T_);
  const float* btab = bias_tab + h * T_;

  // Q fragments (A-operand): lane holds row l16, d = c*32 + g*8 + j
  bf16x8 qf[2];
  {
    const short* qrow = qb + ((size_t)bh * T_ + q0 + w * 16 + l16) * D_;
    qf[0] = *(const bf16x8*)(qrow + g * 8);
    qf[1] = *(const bf16x8*)(qrow + 32 + g * 8);
  }

  f32x4 acc[4] = {};
  float mrun[4], lrun[4];
#pragma unroll
  for (int r = 0; r < 4; ++r) { mrun[r] = -1e30f; lrun[r] = 0.f; }

  char* PsB = (char*)&Ps[w][0];

  int krow[2], kch[2];
#pragma unroll
  for (int i = 0; i < 2; ++i) {
    int o = i * 256 + tid;
    krow[i] = o >> 3;
    kch[i] = (o & 7) ^ (krow[i] & 7);
  }

  // stage K/V tile t into buffer `buf` (async, per-wave slices)
  auto stageKV = [&](int buf, int t) {
    const int kv0 = t * 64;
    char* KsB = (char*)&Ks[buf][0];
    char* VsB = (char*)&Vs[buf][0];
#pragma unroll
    for (int i = 0; i < 2; ++i)
      gload16(kbase + (size_t)(kv0 + krow[i]) * 128 + kch[i] * 16,
              KsB + i * 4096 + w * 1024);
#pragma unroll
    for (int i = 0; i < 2; ++i)
      gload16(vbase + (size_t)krow[i] * (T_ * 2) + kv0 * 2 + kch[i] * 16,
              VsB + i * 4096 + w * 1024);
  };
  // issue bias-window load for tile t (value kept in reg; written to LDS late)
  auto biasLoad = [&](int t) -> float {
    int d = q0 - t * 64 - 63 + tid;
    return (tid < 128 && d >= 0 && d < T_) ? btab[d] : NEG_INF_;
  };

  const int ntiles = qt + 1;
  // prologue: tile 0 into buf 0
  stageKV(0, 0);
  {
    float bv = biasLoad(0);
    if (tid < 128) biasw[0][tid] = bv;
  }
  __syncthreads();

  int cur = 0;
  for (int t = 0; t < ntiles; ++t) {
    const int nxt = cur ^ 1;
    const bool hasnext = (t + 1 < ntiles);
    float bvn = 0.f;
    if (hasnext) {
      stageKV(nxt, t + 1);     // async loads overlap compute below
      bvn = biasLoad(t + 1);   // load issued now, LDS write deferred
    }

    const char* KsB = (const char*)&Ks[cur][0];
    const char* VsB = (const char*)&Vs[cur][0];

    // S = Q*K^T  (4 kv-groups of 16)
    f32x4 s[4];
    __builtin_amdgcn_s_setprio(1);
#pragma unroll
    for (int n = 0; n < 4; ++n) {
      int kvrow = n * 16 + l16;
      int off0 = (kvrow * 128 + g * 16) ^ ((kvrow & 7) << 4);
      int off1 = (kvrow * 128 + 64 + g * 16) ^ ((kvrow & 7) << 4);
      bf16x8 k0 = *(const bf16x8*)(KsB + off0);
      bf16x8 k1 = *(const bf16x8*)(KsB + off1);
      f32x4 z = {};
      z = __builtin_amdgcn_mfma_f32_16x16x32_bf16(qf[0], k0, z, 0, 0, 0);
      z = __builtin_amdgcn_mfma_f32_16x16x32_bf16(qf[1], k1, z, 0, 0, 0);
      s[n] = z;
    }
    __builtin_amdgcn_s_setprio(0);

    // bias (from LDS window) + per-row tile max
    // idx = 63 + (q_in_block) - (kv_in_tile); window holds NEG_INF for dist<0
    float sv[4][4];
    float tmax[4] = {-1e30f, -1e30f, -1e30f, -1e30f};
#pragma unroll
    for (int n = 0; n < 4; ++n) {
#pragma unroll
      for (int r = 0; r < 4; ++r) {
        int idx = 63 + w * 16 + g * 4 + r - n * 16 - l16;
        float val = s[n][r] + biasw[cur][idx];
        sv[n][r] = val;
        tmax[r] = fmaxf(tmax[r], val);
      }
    }
#pragma unroll
    for (int r = 0; r < 4; ++r) {
      float v = tmax[r];
      v = fmaxf(v, __shfl_xor(v, 1));
      v = fmaxf(v, __shfl_xor(v, 2));
      v = fmaxf(v, __shfl_xor(v, 4));
      v = fmaxf(v, __shfl_xor(v, 8));
      tmax[r] = v;
    }

    // online softmax update + write P to wave-private LDS (swizzled)
    float lt[4];
#pragma unroll
    for (int r = 0; r < 4; ++r) {
      float mnew = fmaxf(mrun[r], tmax[r]);
      float scale = __expf(mrun[r] - mnew);
      mrun[r] = mnew;
      lrun[r] *= scale;
#pragma unroll
      for (int dn = 0; dn < 4; ++dn) acc[dn][r] *= scale;
      float su = 0.f;
#pragma unroll
      for (int n = 0; n < 4; ++n) {
        float p = __expf(sv[n][r] - mnew);
        su += p;
        int row = g * 4 + r, col = n * 16 + l16;
        int off = (row * 128 + col * 2) ^ ((row & 7) << 4);
        *(short*)(PsB + off) = f2bf(p);
      }
      lt[r] = su;
    }
#pragma unroll
    for (int r = 0; r < 4; ++r) {
      float v = lt[r];
      v += __shfl_xor(v, 1);
      v += __shfl_xor(v, 2);
      v += __shfl_xor(v, 4);
      v += __shfl_xor(v, 8);
      lrun[r] += v;
    }

    // O += P*V   (P from LDS as A-frag; V^T rows as B-frag)
    bf16x8 pf[2];
    {
      int prow = l16;
      int o0 = (prow * 128 + g * 16) ^ ((prow & 7) << 4);
      int o1 = (prow * 128 + 64 + g * 16) ^ ((prow & 7) << 4);
      pf[0] = *(const bf16x8*)(PsB + o0);
      pf[1] = *(const bf16x8*)(PsB + o1);
    }
    __builtin_amdgcn_s_setprio(1);
#pragma unroll
    for (int dn = 0; dn < 4; ++dn) {
      int drow = dn * 16 + l16;
      int o0 = (drow * 128 + g * 16) ^ ((drow & 7) << 4);
      int o1 = (drow * 128 + 64 + g * 16) ^ ((drow & 7) << 4);
      bf16x8 v0 = *(const bf16x8*)(VsB + o0);
      bf16x8 v1 = *(const bf16x8*)(VsB + o1);
      acc[dn] = __builtin_amdgcn_mfma_f32_16x16x32_bf16(pf[0], v0, acc[dn], 0, 0, 0);
      acc[dn] = __builtin_amdgcn_mfma_f32_16x16x32_bf16(pf[1], v1, acc[dn], 0, 0, 0);
    }
    __builtin_amdgcn_s_setprio(0);

    // deferred bias LDS write for next tile, then barrier (drains vmcnt too)
    if (hasnext && tid < 128) biasw[nxt][tid] = bvn;
    __syncthreads();
    cur = nxt;
  }

  // epilogue: y[b][t][h*64+d] bf16
#pragma unroll
  for (int r = 0; r < 4; ++r) {
    int qg = q0 + w * 16 + g * 4 + r;
    float inv = 1.0f / lrun[r];
    size_t ybase = ((size_t)b * T_ + qg) * C_ + h * D_;
#pragma unroll
    for (int dn = 0; dn < 4; ++dn)
      yb[ybase + dn * 16 + l16] = f2bf(acc[dn][r] * inv);
  }
}

// ---------------------------------------------------------------------------
extern "C" void kernel_launch(void* const* d_in, const int* in_sizes, int n_in,
                              void* d_out, int out_size, void* d_ws, size_t ws_size,
                              hipStream_t stream) {
  const float* x = (const float*)d_in[0];         // [2,2048,1024]
  const float* w_qkv = (const float*)d_in[1];     // [1024,3072]
  const float* w_proj = (const float*)d_in[2];    // [1024,1024]
  const float* rel_table = (const float*)d_in[3]; // [32,16]
  float* out = (float*)d_out;                     // [2,2048,1024]

  const size_t MB = 1024 * 1024;
  char* ws = (char*)d_ws;
  short* xb     = (short*)(ws);             // 8 MB  [4096,1024] bf16
  short* wqkvT  = (short*)(ws + 8 * MB);    // 6 MB  [3072,1024] bf16
  short* wprojT = (short*)(ws + 14 * MB);   // 2 MB  [1024,1024] bf16
  short* qb     = (short*)(ws + 16 * MB);   // 8 MB  [B,H,T,64] bf16 (pre-scaled)
  short* kbuf   = (short*)(ws + 24 * MB);   // 8 MB  [B,H,T,64] bf16
  short* vT     = (short*)(ws + 32 * MB);   // 8 MB  [B,H,64,T] bf16
  short* yb     = (short*)(ws + 40 * MB);   // 8 MB  [4096,1024] bf16
  float* btab   = (float*)(ws + 48 * MB);   // 128 KB [16,2048] fp32

  // 1. conversions
  cvt_bf16<<<4096, 256, 0, stream>>>(x, xb, (B_ * T_ * C_) / 4);
  dim3 tb(32, 8);
  transpose_cvt<<<dim3(96, 32), tb, 0, stream>>>(w_qkv, wqkvT, 1024, 3072);
  transpose_cvt<<<dim3(32, 32), tb, 0, stream>>>(w_proj, wprojT, 1024, 1024);
  bias_table<<<128, 256, 0, stream>>>(rel_table, btab);

  // 2. qkv = x @ w_qkv  (scatter to q/k/vT)
  gemm_bt128<0><<<dim3(24, 32), 256, 0, stream>>>(xb, wqkvT, 4096, 3072, 1024,
                                                  qb, kbuf, vT, nullptr);
  // 3. attention
  attn64<<<dim3(32, 32), 256, 0, stream>>>(qb, kbuf, vT, btab, yb);

  // 4. out = y @ w_proj
  gemm_bt128<1><<<dim3(8, 32), 256, 0, stream>>>(yb, wprojT, 4096, 1024, 1024,
                                                 nullptr, nullptr, nullptr, out);
}

// Round 4
// 220.605 us; speedup vs baseline: 1.2857x; 1.2543x over previous
//
#include <hip/hip_runtime.h>
#include <hip/hip_bf16.h>
#include <cstdint>
#include <cstddef>

// Problem constants
#define B_  2
#define T_  2048
#define C_  1024
#define H_  16
#define D_  64
#define NEG_INF_ -1e9f

typedef short bf16x8 __attribute__((ext_vector_type(8)));
typedef float f32x4  __attribute__((ext_vector_type(4)));

__device__ __forceinline__ short f2bf(float f) {
  union { float f; unsigned u; } x; x.f = f;
  unsigned r = (x.u + 0x7fffu + ((x.u >> 16) & 1u)) >> 16;  // RNE
  return (short)r;
}

__device__ __forceinline__ void gload16(const void* g, void* l) {
  // async global->LDS, 16B per lane; LDS dest = wave-uniform base + lane*16
  __builtin_amdgcn_global_load_lds(
      (const __attribute__((address_space(1))) unsigned int*)g,
      (__attribute__((address_space(3))) unsigned int*)l, 16, 0, 0);
}

// ---------------- fp32 -> bf16 convert (vectorized) ----------------
__global__ __launch_bounds__(256) void cvt_bf16(const float* __restrict__ in,
                                                short* __restrict__ out, int n4) {
  int i = blockIdx.x * 256 + threadIdx.x;
  if (i < n4) {
    float4 v = ((const float4*)in)[i];
    short4 o;
    o.x = f2bf(v.x); o.y = f2bf(v.y); o.z = f2bf(v.z); o.w = f2bf(v.w);
    ((short4*)out)[i] = o;
  }
}

// ---------------- transpose + convert: in[R][C] fp32 -> out[C][R] bf16 ------
__global__ __launch_bounds__(256) void transpose_cvt(const float* __restrict__ in,
                                                     short* __restrict__ out,
                                                     int R, int C) {
  __shared__ float tile[32][33];
  int gx = blockIdx.x * 32, gy = blockIdx.y * 32;
  int tx = threadIdx.x, ty = threadIdx.y;  // (32,8)
#pragma unroll
  for (int i = 0; i < 4; ++i)
    tile[ty + i * 8][tx] = in[(size_t)(gy + ty + i * 8) * C + gx + tx];
  __syncthreads();
#pragma unroll
  for (int i = 0; i < 4; ++i)
    out[(size_t)(gx + ty + i * 8) * R + gy + tx] = f2bf(tile[tx][ty + i * 8]);
}

// ---------------- T5 bias table: bias[h][dist], dist in [0,2048) -----------
__global__ __launch_bounds__(256) void bias_table(const float* __restrict__ rel_table,
                                                  float* __restrict__ btab) {
  int idx = blockIdx.x * 256 + threadIdx.x;  // 16*2048
  if (idx >= H_ * T_) return;
  int dist = idx & (T_ - 1);
  int h = idx >> 11;
  int bucket;
  if (dist < 16) {
    bucket = dist;
  } else {
    float rp = (float)dist;
    int large = 16 + (int)(logf(rp * (1.0f / 16.0f)) * (1.0f / logf(128.0f)) * 16.0f);
    bucket = large < 31 ? large : 31;
  }
  btab[idx] = rel_table[bucket * H_ + h];
}

// ---------------- bf16 GEMM: C[M,N] = A[M,K] * Bt[N,K]^T -------------------
// 128x128 tile, BK=64, 4 waves, 16x16x32 MFMA, global_load_lds(16),
// XOR-swizzled LDS (rows are 128B -> swizzle byte ^= (row&7)<<4).
// MODE 0: scatter epilogue -> q(bf16,*0.125)/k(bf16)/vT(bf16 transposed)
// MODE 1: fp32 out
template <int MODE>
__global__ __launch_bounds__(256) void gemm_bt128(
    const short* __restrict__ A, const short* __restrict__ Bt,
    int M, int N, int K,
    short* __restrict__ q_out, short* __restrict__ k_out,
    short* __restrict__ vT_out, float* __restrict__ f_out) {
  __shared__ alignas(16) short As[128 * 64];
  __shared__ alignas(16) short Bs[128 * 64];
  const int tid = threadIdx.x;
  const int w = tid >> 6, lane = tid & 63;
  const int g = lane >> 4, l16 = lane & 15;
  const int wr = w >> 1, wc = w & 1;
  const int m0 = blockIdx.y * 128, n0 = blockIdx.x * 128;

  const char* Ag = (const char*)(A + (size_t)m0 * K);
  const char* Bg = (const char*)(Bt + (size_t)n0 * K);
  char* AsB = (char*)As;
  char* BsB = (char*)Bs;

  // staging: 1024 16B-chunks per tile, 4 per thread; pre-swizzle source chunk
  int goff[4];
#pragma unroll
  for (int i = 0; i < 4; ++i) {
    int o = i * 256 + tid;
    int row = o >> 3, ch = o & 7;
    goff[i] = row * (K * 2) + ((ch ^ (row & 7)) << 4);
  }

  f32x4 acc[4][4] = {};

  const int nkt = K >> 6;
  for (int kt = 0; kt < nkt; ++kt) {
    __syncthreads();
    const int kbyte = kt << 7;
#pragma unroll
    for (int i = 0; i < 4; ++i)
      gload16(Ag + goff[i] + kbyte, AsB + i * 4096 + w * 1024);
#pragma unroll
    for (int i = 0; i < 4; ++i)
      gload16(Bg + goff[i] + kbyte, BsB + i * 4096 + w * 1024);
    __syncthreads();
#pragma unroll
    for (int kk = 0; kk < 2; ++kk) {
      bf16x8 af[4], bff[4];
#pragma unroll
      for (int m = 0; m < 4; ++m) {
        int r = wr * 64 + m * 16 + l16;
        int off = (r * 128 + kk * 64 + g * 16) ^ ((r & 7) << 4);
        af[m] = *(const bf16x8*)(AsB + off);
      }
#pragma unroll
      for (int n = 0; n < 4; ++n) {
        int c = wc * 64 + n * 16 + l16;
        int off = (c * 128 + kk * 64 + g * 16) ^ ((c & 7) << 4);
        bff[n] = *(const bf16x8*)(BsB + off);
      }
#pragma unroll
      for (int m = 0; m < 4; ++m)
#pragma unroll
        for (int n = 0; n < 4; ++n)
          acc[m][n] = __builtin_amdgcn_mfma_f32_16x16x32_bf16(af[m], bff[n], acc[m][n], 0, 0, 0);
    }
  }

  // epilogue: C/D layout col=lane&15, row=(lane>>4)*4+r
#pragma unroll
  for (int m = 0; m < 4; ++m) {
#pragma unroll
    for (int n = 0; n < 4; ++n) {
      const int colg = n0 + wc * 64 + n * 16 + l16;
#pragma unroll
      for (int r = 0; r < 4; ++r) {
        const int rowg = m0 + wr * 64 + m * 16 + g * 4 + r;
        float v = acc[m][n][r];
        if (MODE == 1) {
          f_out[(size_t)rowg * N + colg] = v;
        } else {
          int part = colg >> 10;
          int within = colg & 1023;
          int h = within >> 6, dd = within & 63;
          int b = rowg >> 11, t = rowg & (T_ - 1);
          size_t bh = (size_t)(b * H_ + h);
          if (part == 0)
            q_out[(bh * T_ + t) * D_ + dd] = f2bf(v * 0.125f);  // fold 1/sqrt(d)
          else if (part == 1)
            k_out[(bh * T_ + t) * D_ + dd] = f2bf(v);
          else
            vT_out[(bh * D_ + dd) * T_ + t] = f2bf(v);  // V transposed
        }
      }
    }
  }
}

// ---------------- flash attention with T5 bias, causal ---------------------
// WORK-BALANCED: block j (0..15) handles q-tiles qlo=j and qhi=31-j
// -> every block does exactly 33 tile-compute units (vs 1..32 before).
// K/V staged once per kv-tile and shared by both q-tiles. 4 waves/block,
// wave w owns 16 q-rows of each q-tile. Double-buffered K/V, LDS bias
// windows (one per q-tile), q pre-scaled by 0.125.
__global__ __launch_bounds__(256) void attn64(
    const short* __restrict__ qb, const short* __restrict__ kb,
    const short* __restrict__ vTb, const float* __restrict__ bias_tab,
    short* __restrict__ yb) {
  __shared__ alignas(16) short Ks[2][64 * 64];
  __shared__ alignas(16) short Vs[2][64 * 64];
  __shared__ alignas(16) short Ps[4][16 * 64];
  __shared__ float biasw[2][2][128];   // [buf][lo/hi][idx]
  const int tid = threadIdx.x;
  const int w = tid >> 6, lane = tid & 63;
  const int g = lane >> 4, l16 = lane & 15;
  const int bh = blockIdx.y;          // b*16 + h
  const int h = bh & (H_ - 1);
  const int b = bh >> 4;
  const int j = blockIdx.x;           // pair index 0..15
  const int qlo = j, qhi = 31 - j;
  const int q0l = qlo * 64, q0h = qhi * 64;

  const char* kbase = (const char*)(kb + (size_t)bh * T_ * D_);
  const char* vbase = (const char*)(vTb + (size_t)bh * D_ * T_);
  const float* btab = bias_tab + h * T_;

  // Q fragments for both q-tiles (A-operand): lane holds row l16
  bf16x8 qfl[2], qfh[2];
  {
    const short* qrl = qb + ((size_t)bh * T_ + q0l + w * 16 + l16) * D_;
    qfl[0] = *(const bf16x8*)(qrl + g * 8);
    qfl[1] = *(const bf16x8*)(qrl + 32 + g * 8);
    const short* qrh = qb + ((size_t)bh * T_ + q0h + w * 16 + l16) * D_;
    qfh[0] = *(const bf16x8*)(qrh + g * 8);
    qfh[1] = *(const bf16x8*)(qrh + 32 + g * 8);
  }

  f32x4 accl[4] = {}, acch[4] = {};
  float ml[4], ll[4], mh[4], lh[4];
#pragma unroll
  for (int r = 0; r < 4; ++r) { ml[r] = mh[r] = -1e30f; ll[r] = lh[r] = 0.f; }

  char* PsB = (char*)&Ps[w][0];

  int krow[2], kch[2];
#pragma unroll
  for (int i = 0; i < 2; ++i) {
    int o = i * 256 + tid;
    krow[i] = o >> 3;
    kch[i] = (o & 7) ^ (krow[i] & 7);
  }

  auto stageKV = [&](int buf, int t) {
    const int kv0 = t * 64;
    char* KsB = (char*)&Ks[buf][0];
    char* VsB = (char*)&Vs[buf][0];
#pragma unroll
    for (int i = 0; i < 2; ++i)
      gload16(kbase + (size_t)(kv0 + krow[i]) * 128 + kch[i] * 16,
              KsB + i * 4096 + w * 1024);
#pragma unroll
    for (int i = 0; i < 2; ++i)
      gload16(vbase + (size_t)krow[i] * (T_ * 2) + kv0 * 2 + kch[i] * 16,
              VsB + i * 4096 + w * 1024);
  };
  // bias window for tile t: threads <128 load lo-window entry, >=128 hi-window
  auto biasLoad = [&](int t) -> float {
    int i = tid & 127;
    int q0x = (tid >= 128) ? q0h : q0l;
    int d = q0x - t * 64 - 63 + i;
    return (d >= 0 && d < T_) ? btab[d] : NEG_INF_;
  };

  // one q-tile's compute against the staged kv-tile
  auto computeTile = [&](const char* KsB, const char* VsB, const float* bw,
                         const bf16x8* qf, f32x4* acc, float* mrun, float* lrun) {
    // S = Q*K^T
    f32x4 s[4];
    __builtin_amdgcn_s_setprio(1);
#pragma unroll
    for (int n = 0; n < 4; ++n) {
      int kvrow = n * 16 + l16;
      int off0 = (kvrow * 128 + g * 16) ^ ((kvrow & 7) << 4);
      int off1 = (kvrow * 128 + 64 + g * 16) ^ ((kvrow & 7) << 4);
      bf16x8 k0 = *(const bf16x8*)(KsB + off0);
      bf16x8 k1 = *(const bf16x8*)(KsB + off1);
      f32x4 z = {};
      z = __builtin_amdgcn_mfma_f32_16x16x32_bf16(qf[0], k0, z, 0, 0, 0);
      z = __builtin_amdgcn_mfma_f32_16x16x32_bf16(qf[1], k1, z, 0, 0, 0);
      s[n] = z;
    }
    __builtin_amdgcn_s_setprio(0);

    // bias from LDS window + per-row tile max
    float sv[4][4];
    float tmax[4] = {-1e30f, -1e30f, -1e30f, -1e30f};
#pragma unroll
    for (int n = 0; n < 4; ++n) {
#pragma unroll
      for (int r = 0; r < 4; ++r) {
        int idx = 63 + w * 16 + g * 4 + r - n * 16 - l16;
        float val = s[n][r] + bw[idx];
        sv[n][r] = val;
        tmax[r] = fmaxf(tmax[r], val);
      }
    }
#pragma unroll
    for (int r = 0; r < 4; ++r) {
      float v = tmax[r];
      v = fmaxf(v, __shfl_xor(v, 1));
      v = fmaxf(v, __shfl_xor(v, 2));
      v = fmaxf(v, __shfl_xor(v, 4));
      v = fmaxf(v, __shfl_xor(v, 8));
      tmax[r] = v;
    }

    // online softmax update + write P to wave-private LDS (swizzled)
    float lt[4];
#pragma unroll
    for (int r = 0; r < 4; ++r) {
      float mnew = fmaxf(mrun[r], tmax[r]);
      float scale = __expf(mrun[r] - mnew);
      mrun[r] = mnew;
      lrun[r] *= scale;
#pragma unroll
      for (int dn = 0; dn < 4; ++dn) acc[dn][r] *= scale;
      float su = 0.f;
#pragma unroll
      for (int n = 0; n < 4; ++n) {
        float p = __expf(sv[n][r] - mnew);
        su += p;
        int row = g * 4 + r, col = n * 16 + l16;
        int off = (row * 128 + col * 2) ^ ((row & 7) << 4);
        *(short*)(PsB + off) = f2bf(p);
      }
      lt[r] = su;
    }
#pragma unroll
    for (int r = 0; r < 4; ++r) {
      float v = lt[r];
      v += __shfl_xor(v, 1);
      v += __shfl_xor(v, 2);
      v += __shfl_xor(v, 4);
      v += __shfl_xor(v, 8);
      lrun[r] += v;
    }

    // O += P*V
    bf16x8 pf[2];
    {
      int o0 = (l16 * 128 + g * 16) ^ ((l16 & 7) << 4);
      int o1 = (l16 * 128 + 64 + g * 16) ^ ((l16 & 7) << 4);
      pf[0] = *(const bf16x8*)(PsB + o0);
      pf[1] = *(const bf16x8*)(PsB + o1);
    }
    __builtin_amdgcn_s_setprio(1);
#pragma unroll
    for (int dn = 0; dn < 4; ++dn) {
      int drow = dn * 16 + l16;
      int o0 = (drow * 128 + g * 16) ^ ((drow & 7) << 4);
      int o1 = (drow * 128 + 64 + g * 16) ^ ((drow & 7) << 4);
      bf16x8 v0 = *(const bf16x8*)(VsB + o0);
      bf16x8 v1 = *(const bf16x8*)(VsB + o1);
      acc[dn] = __builtin_amdgcn_mfma_f32_16x16x32_bf16(pf[0], v0, acc[dn], 0, 0, 0);
      acc[dn] = __builtin_amdgcn_mfma_f32_16x16x32_bf16(pf[1], v1, acc[dn], 0, 0, 0);
    }
    __builtin_amdgcn_s_setprio(0);
  };

  // prologue: tile 0 into buf 0
  stageKV(0, 0);
  {
    float bv = biasLoad(0);
    biasw[0][tid >> 7][tid & 127] = bv;
  }
  __syncthreads();

  int cur = 0;
  for (int t = 0; t <= qhi; ++t) {
    const int nxt = cur ^ 1;
    const bool hasnext = (t < qhi);
    float bvn = 0.f;
    if (hasnext) {
      stageKV(nxt, t + 1);     // async loads overlap the compute below
      bvn = biasLoad(t + 1);   // issued now, LDS write deferred
    }
    if (t <= qlo)
      computeTile((const char*)&Ks[cur][0], (const char*)&Vs[cur][0],
                  &biasw[cur][0][0], qfl, accl, ml, ll);
    computeTile((const char*)&Ks[cur][0], (const char*)&Vs[cur][0],
                &biasw[cur][1][0], qfh, acch, mh, lh);
    if (hasnext) biasw[nxt][tid >> 7][tid & 127] = bvn;
    __syncthreads();
    cur = nxt;
  }

  // epilogue: y[b][t][h*64+d] bf16, both q-tiles
  auto writeO = [&](int q0x, const f32x4* acc, const float* lrun) {
#pragma unroll
    for (int r = 0; r < 4; ++r) {
      int qg = q0x + w * 16 + g * 4 + r;
      float inv = 1.0f / lrun[r];
      size_t ybase = ((size_t)b * T_ + qg) * C_ + h * D_;
#pragma unroll
      for (int dn = 0; dn < 4; ++dn)
        yb[ybase + dn * 16 + l16] = f2bf(acc[dn][r] * inv);
    }
  };
  writeO(q0l, accl, ll);
  writeO(q0h, acch, lh);
}

// ---------------------------------------------------------------------------
extern "C" void kernel_launch(void* const* d_in, const int* in_sizes, int n_in,
                              void* d_out, int out_size, void* d_ws, size_t ws_size,
                              hipStream_t stream) {
  const float* x = (const float*)d_in[0];         // [2,2048,1024]
  const float* w_qkv = (const float*)d_in[1];     // [1024,3072]
  const float* w_proj = (const float*)d_in[2];    // [1024,1024]
  const float* rel_table = (const float*)d_in[3]; // [32,16]
  float* out = (float*)d_out;                     // [2,2048,1024]

  const size_t MB = 1024 * 1024;
  char* ws = (char*)d_ws;
  short* xb     = (short*)(ws);             // 8 MB  [4096,1024] bf16
  short* wqkvT  = (short*)(ws + 8 * MB);    // 6 MB  [3072,1024] bf16
  short* wprojT = (short*)(ws + 14 * MB);   // 2 MB  [1024,1024] bf16
  short* qb     = (short*)(ws + 16 * MB);   // 8 MB  [B,H,T,64] bf16 (pre-scaled)
  short* kbuf   = (short*)(ws + 24 * MB);   // 8 MB  [B,H,T,64] bf16
  short* vT     = (short*)(ws + 32 * MB);   // 8 MB  [B,H,64,T] bf16
  short* yb     = (short*)(ws + 40 * MB);   // 8 MB  [4096,1024] bf16
  float* btab   = (float*)(ws + 48 * MB);   // 128 KB [16,2048] fp32

  // 1. conversions
  cvt_bf16<<<4096, 256, 0, stream>>>(x, xb, (B_ * T_ * C_) / 4);
  dim3 tb(32, 8);
  transpose_cvt<<<dim3(96, 32), tb, 0, stream>>>(w_qkv, wqkvT, 1024, 3072);
  transpose_cvt<<<dim3(32, 32), tb, 0, stream>>>(w_proj, wprojT, 1024, 1024);
  bias_table<<<128, 256, 0, stream>>>(rel_table, btab);

  // 2. qkv = x @ w_qkv  (scatter to q/k/vT)
  gemm_bt128<0><<<dim3(24, 32), 256, 0, stream>>>(xb, wqkvT, 4096, 3072, 1024,
                                                  qb, kbuf, vT, nullptr);
  // 3. attention (work-balanced q-tile pairs)
  attn64<<<dim3(16, 32), 256, 0, stream>>>(qb, kbuf, vT, btab, yb);

  // 4. out = y @ w_proj
  gemm_bt128<1><<<dim3(8, 32), 256, 0, stream>>>(yb, wprojT, 4096, 1024, 1024,
                                                 nullptr, nullptr, nullptr, out);
}